// Round 9
// baseline (316.247 us; speedup 1.0000x reference)
//
#include <hip/hip_runtime.h>
#include <hip/hip_bf16.h>

#define BB      4
#define NTOK    6273      // 1 + 8*28*28
#define NPOOL   1569      // 1 + 8*14*14
#define NPOOLP  1600      // padded kv length (25 * 64)
#define NHEADS  12
#define TT      8
#define HH      28
#define WW      28
#define HP      14
#define WP      14

typedef __attribute__((ext_vector_type(8))) _Float16 f16x8;
typedef __attribute__((ext_vector_type(4))) float f32x4;
typedef unsigned short u16;

#define AS1(p) ((const __attribute__((address_space(1))) void*)(p))
#define AS3(p) ((__attribute__((address_space(3))) void*)(p))

static __device__ __forceinline__ u16 f2h(float x) {
    union { _Float16 h; u16 u; } c; c.h = (_Float16)x; return c.u;
}
static __device__ __forceinline__ float h2f(u16 u) {
    union { u16 u; _Float16 h; } c; c.u = u; return (float)c.h;
}

// ---------------------------------------------------------------------------
// Flat fp32 -> fp16 convert (x pre-pass).
// ---------------------------------------------------------------------------
__global__ __launch_bounds__(256) void cvt_f32_f16_kernel(
    const float* __restrict__ in, u16* __restrict__ out, int n4)
{
    int i = blockIdx.x * 256 + threadIdx.x;
    const int stride = gridDim.x * 256;
    for (; i < n4; i += stride) {
        const float4 v = ((const float4*)in)[i];
        ushort4 o;
        o.x = f2h(v.x); o.y = f2h(v.y); o.z = f2h(v.z); o.w = f2h(v.w);
        ((ushort4*)out)[i] = o;
    }
}

// ---------------------------------------------------------------------------
// Transpose + convert: W[K][N] fp32 -> t [N][K] fp16
// ---------------------------------------------------------------------------
__global__ __launch_bounds__(256) void transpose_cvt_kernel(
    const float* __restrict__ W, u16* __restrict__ t, int K, int N)
{
    __shared__ float tile[32][33];
    const int n0 = blockIdx.x * 32, k0 = blockIdx.y * 32;
    const int tx = threadIdx.x, ty = threadIdx.y;   // block (32,8)
    #pragma unroll
    for (int i = 0; i < 4; ++i)
        tile[ty + i * 8][tx] = W[(size_t)(k0 + ty + i * 8) * N + n0 + tx];
    __syncthreads();
    #pragma unroll
    for (int i = 0; i < 4; ++i) {
        const int n = n0 + ty + i * 8;
        t[(size_t)n * K + k0 + tx] = f2h(tile[tx][ty + i * 8]);
    }
}

// ---------------------------------------------------------------------------
// Conv-weight transpose: w[64][27] fp32 -> wTh[which][27][64] fp16.
// ---------------------------------------------------------------------------
__global__ __launch_bounds__(256) void wt_transpose_kernel(
    const float* __restrict__ wq, const float* __restrict__ wk,
    const float* __restrict__ wv, u16* __restrict__ wTh)
{
    const int which = blockIdx.x;
    const float* w = (which == 0) ? wq : (which == 1) ? wk : wv;
    u16* o = wTh + which * 27 * 64;
    for (int i = threadIdx.x; i < 27 * 64; i += 256) {
        const int j = i >> 6, d = i & 63;
        o[j * 64 + d] = f2h(w[d * 27 + j]);
    }
}

// ---------------------------------------------------------------------------
// QKV GEMM: round-21 K-loop FROZEN (121.5us, 0 conflicts).  Round-28 change
// is EPILOGUE-ONLY: the old epilogue issued 64 scalar u16 stores/thread,
// each wave-instr touching 4 scattered 32B segments (half-efficiency HBM
// bursts, no write combining).  New: LDS-transpose epilogue — reuse the
// staging LDS (one SMEM block, A/B views) as a per-wave C-buffer; write the
// 64x64 wave tile (fp16, bias applied) in two 32-row halves at 72-u16 pitch,
// __syncthreads, read back contiguous half-rows, store 4x16B fully-coalesced
// (the 64-col range = one head's d0..63 => 128B contiguous per row).
// 8x16B stores/thread replace 64x2B.  __syncthreads-only sync (round-7 rule).
// ---------------------------------------------------------------------------
#define GBK 32
#define GNKT 24           // 768 / 32

__global__ __launch_bounds__(512, 4) void gemm256_qkv_kernel(
    const u16* __restrict__ Af, const u16* __restrict__ Bt,
    const float* __restrict__ bias, int M,
    u16* __restrict__ o0, u16* __restrict__ o1, u16* __restrict__ o2)
{
    __shared__ __align__(16) u16 SMEM[24576];   // 48 KiB
    // views: A_s[buf] = SMEM + buf*8192 (256x32), B_s[buf] = SMEM+16384+buf*4096
    #define A_S(buf) (&SMEM[(buf) * 8192])
    #define B_S(buf) (&SMEM[16384 + (buf) * 4096])

    const int tid  = threadIdx.x;
    const int lane = tid & 63;
    const int w    = tid >> 6;          // 0..7
    const int wr   = w >> 1, wc = w & 1;   // 4 x 2 wave grid, wave tile 64x64

    // bijective XCD-aware swizzle (nwg = 1782)
    const int nwg = gridDim.x;
    const int qch = nwg >> 3, rch = nwg & 7;
    const int xcd = blockIdx.x & 7, idx = blockIdx.x >> 3;
    const int wg  = (xcd < rch ? xcd * (qch + 1) : rch * (qch + 1) + (xcd - rch) * qch) + idx;
    const int m0 = (wg / 18) * 256;
    const int nb = wg % 18;
    const int n0 = nb * 128;

    // staging: A tile 256x32 u16 = 1024 16B-chunks (2/thread),
    //          B tile 128x32 u16 =  512 16B-chunks (1/thread).
    // LDS dest linear; source col pre-swizzled chunk ^= ((row>>1)&3).
    const int rA0 = tid >> 2;
    const int cA0 = ((tid & 3) ^ ((rA0 >> 1) & 3)) << 3;
    const int ch1 = 512 + tid;
    const int rA1 = ch1 >> 2;
    const int cA1 = ((ch1 & 3) ^ ((rA1 >> 1) & 3)) << 3;
    const u16* pA0 = Af + (size_t)min(m0 + rA0, M - 1) * 768 + cA0;
    const u16* pA1 = Af + (size_t)min(m0 + rA1, M - 1) * 768 + cA1;
    const u16* pB  = Bt + (size_t)(n0 + rA0) * 768 + cA0;
    const int dstA0 = (w * 64) * 8;          // u16 index (lane*16B implicit)
    const int dstA1 = (512 + w * 64) * 8;
    const int dstB  = (w * 64) * 8;

    #define STAGE(buf, kk) do { \
        __builtin_amdgcn_global_load_lds(AS1(pA0 + (kk)), AS3(&A_S(buf)[dstA0]), 16, 0, 0); \
        __builtin_amdgcn_global_load_lds(AS1(pA1 + (kk)), AS3(&A_S(buf)[dstA1]), 16, 0, 0); \
        __builtin_amdgcn_global_load_lds(AS1(pB  + (kk)), AS3(&B_S(buf)[dstB ]), 16, 0, 0); \
    } while (0)

    STAGE(0, 0);   // prologue: tile 0 in flight (3 loads/wave)

    f32x4 acc[4][4] = {};
    const int fr = lane & 15, fq = lane >> 4;
    const int sw8 = (fq ^ ((fr >> 1) & 3)) << 3;

    for (int t = 0; t < GNKT; ++t) {
        const int cur = t & 1;
        if (t < GNKT - 1) {
            STAGE(cur ^ 1, (t + 1) * GBK);
            asm volatile("s_waitcnt vmcnt(3)" ::: "memory");   // tile t landed
        } else {
            asm volatile("s_waitcnt vmcnt(0)" ::: "memory");
        }
        __builtin_amdgcn_s_barrier();

        f16x8 a[4], b[4];
        #pragma unroll
        for (int m = 0; m < 4; ++m)
            a[m] = *(const f16x8*)&A_S(cur)[(wr * 64 + m * 16 + fr) * GBK + sw8];
        #pragma unroll
        for (int n = 0; n < 4; ++n)
            b[n] = *(const f16x8*)&B_S(cur)[(wc * 64 + n * 16 + fr) * GBK + sw8];

        __builtin_amdgcn_s_setprio(1);
        #pragma unroll
        for (int m = 0; m < 4; ++m)
            #pragma unroll
            for (int n = 0; n < 4; ++n)
                acc[m][n] = __builtin_amdgcn_mfma_f32_16x16x32_f16(a[m], b[n], acc[m][n], 0, 0, 0);
        __builtin_amdgcn_s_setprio(0);

        if (t < GNKT - 1) __builtin_amdgcn_s_barrier();   // release buf[cur]
    }
    #undef STAGE

    // ---- round-28 LDS-transpose epilogue ----
    __syncthreads();   // all waves' last ds_reads done; LDS free for C

    const int colbase = n0 + wc * 64;                // 64-aligned => one head
    const int s = nb / 6;
    u16* const dsts = (s == 0) ? o0 : (s == 1) ? o1 : o2;
    const int hh = (colbase - s * 768) >> 6;         // head idx, const per wave-col

    float bsv[4];
    #pragma unroll
    for (int n = 0; n < 4; ++n)
        bsv[n] = bias[colbase + n * 16 + fr];

    u16* const Cw = &SMEM[w * 2304];                 // 32 rows x 72 u16 = 4608 B
    const int r2 = lane >> 1, half = lane & 1;

    #pragma unroll
    for (int mh = 0; mh < 2; ++mh) {
        // write half-tile (rows m = mh*2+mm) as fp16 with bias
        #pragma unroll
        for (int mm = 0; mm < 2; ++mm)
            #pragma unroll
            for (int n = 0; n < 4; ++n)
                #pragma unroll
                for (int j = 0; j < 4; ++j)
                    Cw[(mm * 16 + fq * 4 + j) * 72 + n * 16 + fr] =
                        f2h(acc[mh * 2 + mm][n][j] + bsv[n]);
        __syncthreads();

        // read back contiguous half-row; store 4x16B coalesced
        const int grow = m0 + wr * 64 + mh * 32 + r2;
        if (grow < M) {
            const int bidx = grow / NTOK;
            const int ntok = grow - bidx * NTOK;
            u16* dst = &dsts[(size_t)((bidx * NHEADS + hh) * NTOK + ntok) * 64 + half * 32];
            const u16* src = &Cw[r2 * 72 + half * 32];
            #pragma unroll
            for (int i = 0; i < 4; ++i)
                *(uint4*)&dst[i * 8] = *(const uint4*)&src[i * 8];
        }
        if (mh == 0) __syncthreads();   // before overwriting Cw
    }
    #undef A_S
    #undef B_S
}

// ---------------------------------------------------------------------------
// Single-term fp16 MFMA GEMM — round-17 version; used for proj only.
// ---------------------------------------------------------------------------
template<int NBLK, bool QKV, typename OutT>
__global__ __launch_bounds__(512) void gemm_fp16_kernel(
    const u16* __restrict__ Af, const u16* __restrict__ Bt,
    const float* __restrict__ bias, int M,
    OutT* __restrict__ o0, OutT* __restrict__ o1, OutT* __restrict__ o2)
{
    __shared__ __align__(16) u16 A_s[128 * 32];
    __shared__ __align__(16) u16 B_s[128 * 32];

    const int tid  = threadIdx.x;
    const int lane = tid & 63;
    const int w    = tid >> 6;          // 0..7
    const int wr   = w >> 2, wc = w & 3;

    const int nwg = gridDim.x;
    const int qch = nwg >> 3, rch = nwg & 7;
    const int xcd = blockIdx.x & 7, idx = blockIdx.x >> 3;
    const int wg  = (xcd < rch ? xcd * (qch + 1) : rch * (qch + 1) + (xcd - rch) * qch) + idx;
    const int m0 = (wg / NBLK) * 128;
    const int n0 = (wg % NBLK) * 128;

    f32x4 acc[4][2] = {};

    const int srow   = lane >> 2;                        // 0..15
    const int sslot  = (lane & 3) ^ ((srow >> 1) & 3);   // logical 16B chunk

    for (int kt = 0; kt < 24; ++kt) {
        const int k0 = kt * 32;
        __syncthreads();

        {
            const int rb = w * 16;
            const int ra = min(m0 + rb + srow, M - 1);
            __builtin_amdgcn_global_load_lds(AS1(Af + (size_t)ra * 768 + k0 + sslot * 8),
                                             AS3(&A_s[rb * 32]), 16, 0, 0);
            __builtin_amdgcn_global_load_lds(AS1(Bt + (size_t)(n0 + rb + srow) * 768 + k0 + sslot * 8),
                                             AS3(&B_s[rb * 32]), 16, 0, 0);
        }
        __syncthreads();

        const int fr = lane & 15, fq = lane >> 4;
        const int rslot = (fq ^ ((fr >> 1) & 3)) << 3;
        f16x8 a[4], b[2];
        #pragma unroll
        for (int m = 0; m < 4; ++m)
            a[m] = *(const f16x8*)&A_s[(wr * 64 + m * 16 + fr) * 32 + rslot];
        #pragma unroll
        for (int n = 0; n < 2; ++n)
            b[n] = *(const f16x8*)&B_s[(wc * 32 + n * 16 + fr) * 32 + rslot];

        #pragma unroll
        for (int m = 0; m < 4; ++m)
            #pragma unroll
            for (int n = 0; n < 2; ++n)
                acc[m][n] = __builtin_amdgcn_mfma_f32_16x16x32_f16(a[m], b[n], acc[m][n], 0, 0, 0);
    }

    const int fr = lane & 15, fq = lane >> 4;
    #pragma unroll
    for (int m = 0; m < 4; ++m) {
        const int grow_base = m0 + wr * 64 + m * 16 + fq * 4;
        #pragma unroll
        for (int j = 0; j < 4; ++j) {
            const int grow = grow_base + j;
            if (grow >= M) continue;
            int b = 0, ntok = 0;
            if (QKV) { b = grow / NTOK; ntok = grow - b * NTOK; }
            #pragma unroll
            for (int n = 0; n < 2; ++n) {
                const int gcol = n0 + wc * 32 + n * 16 + fr;
                const float v = acc[m][n][j] + bias[gcol];
                if (QKV) {
                    const int s = gcol / 768;
                    const int rem = gcol - s * 768;
                    const int h = rem >> 6, d = rem & 63;
                    OutT* dst = (s == 0) ? o0 : (s == 1) ? o1 : o2;
                    dst[(size_t)((b * NHEADS + h) * NTOK + ntok) * 64 + d] = (OutT)f2h(v);
                } else {
                    o0[(size_t)grow * (NBLK * 128) + gcol] = (OutT)v;
                }
            }
        }
    }
}

// ---------------------------------------------------------------------------
// Depthwise conv3d + LayerNorm(64), round-18 version (proven, unchanged):
// vector-select masking; V written directly transposed with zero pad.
// ---------------------------------------------------------------------------
#define PL_PG  50                 // 32-token groups per (which,bh)
#define PL_NWG (3 * 48 * PL_PG)   // 7200
__global__ __launch_bounds__(256) void pool_ln_kernel(
    const u16* __restrict__ qr, const u16* __restrict__ kr, const u16* __restrict__ vr,
    const u16* __restrict__ wTh,
    const float* __restrict__ gq, const float* __restrict__ bq,
    const float* __restrict__ gk, const float* __restrict__ bk,
    const float* __restrict__ gv, const float* __restrict__ bv,
    u16* __restrict__ qph, u16* __restrict__ kph, u16* __restrict__ vpt)
{
    const int wg = (blockIdx.x & 7) * (PL_NWG / 8) + (blockIdx.x >> 3);
    const int which = wg / (48 * PL_PG);
    const int rem   = wg - which * (48 * PL_PG);
    const int bh    = rem / PL_PG;
    const int pg    = rem - bh * PL_PG;
    const int wv_   = threadIdx.x >> 6;
    const int lane  = threadIdx.x & 63;
    const int tg    = lane >> 3;
    const int d0    = (lane & 7) * 8;

    const int p  = pg * 32 + wv_ * 8 + tg;
    const int pc = min(p, NPOOL - 1);

    const u16*   in  = (which == 0) ? qr : (which == 1) ? kr : vr;
    const u16*   wTb = wTh + which * 27 * 64;
    const float* g   = (which == 0) ? gq : (which == 1) ? gk : gv;
    const float* bb_ = (which == 0) ? bq : (which == 1) ? bk : bv;
    const float qscale = (which == 0) ? 0.125f : 1.0f;

    const size_t inb = (size_t)bh * NTOK * 64;

    float s[8] = {};
    if (pc == 0) {
        const f16x8 t = *(const f16x8*)&in[inb + d0];
        #pragma unroll
        for (int c = 0; c < 8; ++c) s[c] = (float)t[c];
    } else {
        const int idx = pc - 1;
        const int tp = idx / (HP * WP);
        const int r2 = idx - tp * (HP * WP);
        const int hp = r2 / WP;
        const int wp = r2 - hp * WP;

        const f16x8 z8 = (f16x8)(_Float16)0.0f;
        #pragma unroll
        for (int kt = 0; kt < 3; ++kt) {
            const int it = tp + kt - 1;
            #pragma unroll
            for (int kh = 0; kh < 3; ++kh) {
                const int ih = hp * 2 + kh - 1;
                #pragma unroll
                for (int kw = 0; kw < 3; ++kw) {
                    const int iw = wp * 2 + kw - 1;
                    const int j  = kt * 9 + kh * 3 + kw;
                    const bool ok = (it >= 0) & (it < TT) & (ih >= 0) & (ih < HH) &
                                    (iw >= 0) & (iw < WW);
                    const int n   = 1 + (it * HH + ih) * WW + iw;
                    const int n_c = ok ? n : 0;            // always valid token
                    const f16x8 tv  = *(const f16x8*)&in[inb + (size_t)n_c * 64 + d0];
                    const f16x8 wv8 = *(const f16x8*)&wTb[j * 64 + d0];
                    const f16x8 ts  = ok ? tv : z8;        // zero by SELECT
                    #pragma unroll
                    for (int c = 0; c < 8; ++c)
                        s[c] = fmaf((float)wv8[c], (float)ts[c], s[c]);
                }
            }
        }
    }

    float sum = 0.f, ssq = 0.f;
    #pragma unroll
    for (int c = 0; c < 8; ++c) { sum += s[c]; ssq += s[c] * s[c]; }
    #pragma unroll
    for (int off = 1; off < 8; off <<= 1) {
        sum += __shfl_xor(sum, off);
        ssq += __shfl_xor(ssq, off);
    }
    const float mu  = sum * (1.f / 64.f);
    const float var = ssq * (1.f / 64.f) - mu * mu;
    const float rs  = rsqrtf(var + 1e-5f);

    float g8[8], b8[8];
    {
        const float4 g0 = *(const float4*)&g[d0];
        const float4 g1 = *(const float4*)&g[d0 + 4];
        const float4 b0 = *(const float4*)&bb_[d0];
        const float4 b1 = *(const float4*)&bb_[d0 + 4];
        g8[0]=g0.x; g8[1]=g0.y; g8[2]=g0.z; g8[3]=g0.w;
        g8[4]=g1.x; g8[5]=g1.y; g8[6]=g1.z; g8[7]=g1.w;
        b8[0]=b0.x; b8[1]=b0.y; b8[2]=b0.z; b8[3]=b0.w;
        b8[4]=b1.x; b8[5]=b1.y; b8[6]=b1.z; b8[7]=b1.w;
    }

    u16 oo[8];
    #pragma unroll
    for (int c = 0; c < 8; ++c)
        oo[c] = f2h(((s[c] - mu) * rs * g8[c] + b8[c]) * qscale);

    if (which == 2) {
        u16* base = vpt + (size_t)bh * 64 * NPOOLP + p;
        if (p < NPOOL) {
            #pragma unroll
            for (int c = 0; c < 8; ++c)
                base[(size_t)(d0 + c) * NPOOLP] = oo[c];
        } else {
            #pragma unroll
            for (int c = 0; c < 8; ++c)
                base[(size_t)(d0 + c) * NPOOLP] = 0;
        }
    } else if (p < NPOOL) {
        u16* out = (which == 0) ? qph : kph;
        u16* dst = &out[((size_t)bh * NPOOL + p) * 64 + d0];
        *(ushort4*)&dst[0] = *(ushort4*)&oo[0];
        *(ushort4*)&dst[4] = *(ushort4*)&oo[4];
    }
}

// ---------------------------------------------------------------------------
// Round-27 flash attention (passing): single-pass + double-buffered K/V
// prefetch with __syncthreads-only synchronization.  UNCHANGED.
// ---------------------------------------------------------------------------
__global__ __launch_bounds__(256) void flash_attn_fp16_kernel(
    const u16* __restrict__ qh, const u16* __restrict__ kh,
    const u16* __restrict__ vt, u16* __restrict__ aoh)
{
    __shared__ __align__(16) u16 K_s[2][64 * 64];
    __shared__ __align__(16) u16 V_s[2][64 * 64];
    __shared__ __align__(16) u16 P_s[4][16 * 64];

    const int bh = blockIdx.y;
    const int q0 = blockIdx.x * 64;
    const int tid = threadIdx.x;
    const int w = tid >> 6, lane = tid & 63;
    const int fr = lane & 15, fq = lane >> 4;
    const int l8 = lane >> 3;
    const int sw = 8 * ((lane & 7) ^ l8);

    const size_t hb  = (size_t)bh * NPOOL * 64;
    const size_t vtb = (size_t)bh * 64 * NPOOLP;

    f16x8 qf_[2];
    {
        const int row = min(q0 + w * 16 + fr, NPOOL - 1);
        #pragma unroll
        for (int half = 0; half < 2; ++half)
            qf_[half] = *(const f16x8*)&qh[hb + (size_t)row * 64 + half * 32 + fq * 8];
    }

    f16x8 ones;
    #pragma unroll
    for (int i = 0; i < 8; ++i) ones[i] = (_Float16)1.0f;

    f32x4 acc[4] = {};
    f32x4 l_acc = {};

    #define STAGEKV(buf, kt) do { \
        _Pragma("unroll") \
        for (int i = 0; i < 2; ++i) { \
            const int rb = w * 16 + i * 8; \
            const int r  = rb + l8; \
            const int gk = min((kt) * 64 + r, NPOOL - 1); \
            __builtin_amdgcn_global_load_lds(AS1(kh + hb + (size_t)gk * 64 + sw), \
                                             AS3(&K_s[buf][rb * 64]), 16, 0, 0); \
            __builtin_amdgcn_global_load_lds(AS1(vt + vtb + (size_t)r * NPOOLP + (kt) * 64 + sw), \
                                             AS3(&V_s[buf][rb * 64]), 16, 0, 0); \
        } \
    } while (0)

    #define LDSW(buf, row, colbyte) \
        (*(const f16x8*)((const char*)(buf) + ((row) * 128 + ((colbyte) ^ (((row) & 7) << 4)))))

    STAGEKV(0, 0);     // tile 0 in flight
    __syncthreads();   // tile 0 landed (full drain), waves synced

    for (int kt = 0; kt < 25; ++kt) {
        const int cur = kt & 1;
        if (kt < 24) STAGEKV(cur ^ 1, kt + 1);

        const int k0 = kt * 64;
        f32x4 sv[4];
        #pragma unroll
        for (int nf = 0; nf < 4; ++nf) {
            const int krow = nf * 16 + fr;
            const f16x8 kf0 = LDSW(&K_s[cur][0], krow, fq * 16);
            const f16x8 kf1 = LDSW(&K_s[cur][0], krow, 64 + fq * 16);
            f32x4 s = {};
            s = __builtin_amdgcn_mfma_f32_16x16x32_f16(qf_[0], kf0, s, 0, 0, 0);
            s = __builtin_amdgcn_mfma_f32_16x16x32_f16(qf_[1], kf1, s, 0, 0, 0);
            sv[nf] = s;
        }

        #pragma unroll
        for (int nf = 0; nf < 4; ++nf) {
            const bool valid = (k0 + nf * 16 + fr) < NPOOL;
            #pragma unroll
            for (int j = 0; j < 4; ++j) {
                const float p = valid ? __expf(sv[nf][j]) : 0.f;
                const int row = fq * 4 + j;
                const int bo  = row * 128 + ((nf * 32 + fr * 2) ^ ((row & 7) << 4));
                *(u16*)((char*)&P_s[w][0] + bo) = f2h(p);
            }
        }
        __builtin_amdgcn_sched_barrier(0);

        const f16x8 pa0 = LDSW(&P_s[w][0], fr, fq * 16);
        const f16x8 pa1 = LDSW(&P_s[w][0], fr, 64 + fq * 16);
        l_acc = __builtin_amdgcn_mfma_f32_16x16x32_f16(pa0, ones, l_acc, 0, 0, 0);
        l_acc = __builtin_amdgcn_mfma_f32_16x16x32_f16(pa1, ones, l_acc, 0, 0, 0);
        #pragma unroll
        for (int df = 0; df < 4; ++df) {
            const int vrow = df * 16 + fr;
            const f16x8 v0 = LDSW(&V_s[cur][0], vrow, fq * 16);
            const f16x8 v1 = LDSW(&V_s[cur][0], vrow, 64 + fq * 16);
            acc[df] = __builtin_amdgcn_mfma_f32_16x16x32_f16(pa0, v0, acc[df], 0, 0, 0);
            acc[df] = __builtin_amdgcn_mfma_f32_16x16x32_f16(pa1, v1, acc[df], 0, 0, 0);
        }

        __syncthreads();
    }
    #undef LDSW
    #undef STAGEKV

    const int b = bh / NHEADS, h = bh % NHEADS;
    #pragma unroll
    for (int j = 0; j < 4; ++j) {
        const int q = q0 + w * 16 + fq * 4 + j;
        if (q >= NPOOL) continue;
        const float inv = 1.f / l_acc[j];
        u16* dst = &aoh[((size_t)(b * NPOOL + q)) * 768 + h * 64];
        #pragma unroll
        for (int df = 0; df < 4; ++df)
            dst[df * 16 + fr] = f2h(acc[df][j] * inv);
    }
}

// ---------------------------------------------------------------------------
extern "C" void kernel_launch(void* const* d_in, const int* in_sizes, int n_in,
                              void* d_out, int out_size, void* d_ws, size_t ws_size,
                              hipStream_t stream)
{
    const float* x      = (const float*)d_in[0];
    const float* qkv_w  = (const float*)d_in[1];
    const float* qkv_b  = (const float*)d_in[2];
    const float* proj_w = (const float*)d_in[3];
    const float* proj_b = (const float*)d_in[4];
    const float* wq     = (const float*)d_in[5];
    const float* wk     = (const float*)d_in[6];
    const float* wv     = (const float*)d_in[7];
    const float* gq     = (const float*)d_in[8];
    const float* bq     = (const float*)d_in[9];
    const float* gk     = (const float*)d_in[10];
    const float* bk     = (const float*)d_in[11];
    const float* gv     = (const float*)d_in[12];
    const float* bv     = (const float*)d_in[13];

    const size_t RAW  = (size_t)BB * NHEADS * NTOK * 64;   // 19,270,656 (= M*768)
    const size_t PLD  = (size_t)BB * NHEADS * NPOOL * 64;
    const size_t VTSZ = (size_t)BB * NHEADS * 64 * NPOOLP;

    u16* q_raw = (u16*)d_ws;          // fp16
    u16* k_raw = q_raw + RAW;
    u16* v_raw = k_raw + RAW;
    u16* xh    = v_raw + RAW;
    u16* qph   = xh + RAW;
    u16* kph   = qph + PLD;
    u16* vpb   = kph + PLD;          // unused (layout stability)
    u16* vpt   = vpb + PLD;
    u16* wth   = vpt + VTSZ;
    u16* pwth  = wth + (size_t)2304 * 768;
    u16* wTh   = pwth + (size_t)768 * 768;   // 3*27*64 fp16
    u16* aoh   = q_raw;               // q_raw dead after pool_ln

    cvt_f32_f16_kernel<<<2048, 256, 0, stream>>>(x, xh, (int)(RAW / 4));

    transpose_cvt_kernel<<<dim3(2304 / 32, 768 / 32), dim3(32, 8), 0, stream>>>(
        qkv_w, wth, 768, 2304);
    transpose_cvt_kernel<<<dim3(768 / 32, 768 / 32), dim3(32, 8), 0, stream>>>(
        proj_w, pwth, 768, 768);
    wt_transpose_kernel<<<3, 256, 0, stream>>>(wq, wk, wv, wTh);

    // 256x128 tiles: ceil(25092/256)=99 M-tiles x 18 N-tiles = 1782 blocks
    gemm256_qkv_kernel<<<dim3(99 * 18), 512, 0, stream>>>(
        xh, wth, qkv_b, BB * NTOK, q_raw, k_raw, v_raw);

    pool_ln_kernel<<<dim3(PL_NWG), 256, 0, stream>>>(
        q_raw, k_raw, v_raw, wTh, gq, bq, gk, bk, gv, bv,
        qph, kph, vpt);

    // single-pass attention: 25 q-tiles x 48 heads, fp16 out, no combine
    flash_attn_fp16_kernel<<<dim3(25, 48), 256, 0, stream>>>(
        qph, kph, vpt, aoh);

    gemm_fp16_kernel<6, false, float><<<dim3(50 * 6), 512, 0, stream>>>(
        aoh, pwth, proj_b, BB * NPOOL, (float*)d_out, nullptr, nullptr);
}

// Round 10
// 291.889 us; speedup vs baseline: 1.0834x; 1.0834x over previous
//
#include <hip/hip_runtime.h>
#include <hip/hip_bf16.h>

#define BB      4
#define NTOK    6273      // 1 + 8*28*28
#define NPOOL   1569      // 1 + 8*14*14
#define NPOOLP  1600      // padded kv length (25 * 64)
#define NHEADS  12
#define TT      8
#define HH      28
#define WW      28
#define HP      14
#define WP      14

typedef __attribute__((ext_vector_type(8))) _Float16 f16x8;
typedef __attribute__((ext_vector_type(4))) float f32x4;
typedef unsigned short u16;

#define AS1(p) ((const __attribute__((address_space(1))) void*)(p))
#define AS3(p) ((__attribute__((address_space(3))) void*)(p))

static __device__ __forceinline__ u16 f2h(float x) {
    union { _Float16 h; u16 u; } c; c.h = (_Float16)x; return c.u;
}
static __device__ __forceinline__ float h2f(u16 u) {
    union { u16 u; _Float16 h; } c; c.u = u; return (float)c.h;
}

// ---------------------------------------------------------------------------
// Flat fp32 -> fp16 convert (x pre-pass).
// ---------------------------------------------------------------------------
__global__ __launch_bounds__(256) void cvt_f32_f16_kernel(
    const float* __restrict__ in, u16* __restrict__ out, int n4)
{
    int i = blockIdx.x * 256 + threadIdx.x;
    const int stride = gridDim.x * 256;
    for (; i < n4; i += stride) {
        const float4 v = ((const float4*)in)[i];
        ushort4 o;
        o.x = f2h(v.x); o.y = f2h(v.y); o.z = f2h(v.z); o.w = f2h(v.w);
        ((ushort4*)out)[i] = o;
    }
}

// ---------------------------------------------------------------------------
// Round-29 merged prep: one launch covering
//   blocks [0, 1728)        : transpose_cvt qkv_w  (768x2304 -> wth)
//   blocks [1728, 2304)     : transpose_cvt proj_w (768x768  -> pwth)
//   blocks [2304, 2307)     : wt_transpose  wq/wk/wv -> wTh
// Bodies verbatim from the proven kernels; only the dispatch is new.
// Saves 2 kernel launches (+ tail/ramp bubbles) in the 7-launch chain.
// ---------------------------------------------------------------------------
__global__ __launch_bounds__(256) void prep_kernel(
    const float* __restrict__ qkv_w, const float* __restrict__ proj_w,
    const float* __restrict__ wq, const float* __restrict__ wk,
    const float* __restrict__ wv,
    u16* __restrict__ wth, u16* __restrict__ pwth, u16* __restrict__ wTh)
{
    __shared__ float tile[32][33];
    const int b = blockIdx.x;
    const int tx = threadIdx.x & 31, ty = threadIdx.x >> 5;   // (32,8) layout

    if (b < 2304) {
        const float* W; u16* t; int K, N, n0, k0;
        if (b < 1728) {
            W = qkv_w; t = wth; K = 768; N = 2304;
            n0 = (b % 72) * 32; k0 = (b / 72) * 32;
        } else {
            const int ib = b - 1728;
            W = proj_w; t = pwth; K = 768; N = 768;
            n0 = (ib % 24) * 32; k0 = (ib / 24) * 32;
        }
        #pragma unroll
        for (int i = 0; i < 4; ++i)
            tile[ty + i * 8][tx] = W[(size_t)(k0 + ty + i * 8) * N + n0 + tx];
        __syncthreads();
        #pragma unroll
        for (int i = 0; i < 4; ++i) {
            const int n = n0 + ty + i * 8;
            t[(size_t)n * K + k0 + tx] = f2h(tile[tx][ty + i * 8]);
        }
    } else {
        const int which = b - 2304;
        const float* w = (which == 0) ? wq : (which == 1) ? wk : wv;
        u16* o = wTh + which * 27 * 64;
        for (int i = threadIdx.x; i < 27 * 64; i += 256) {
            const int j = i >> 6, d = i & 63;
            o[j * 64 + d] = f2h(w[d * 27 + j]);
        }
    }
}

// ---------------------------------------------------------------------------
// QKV GEMM: round-21 version REVERTED VERBATIM (best measured: 121.5us,
// 0 bank conflicts, VGPR 56, occ 39%).  Round-28's LDS-transpose epilogue
// REGRESSED (dur +4us, FETCH +22MB from partial-line write-allocate RMW,
// VALUBusy 27->19): the scattered-store theory was wrong — write path was
// not binding.  FROZEN at this form.
// ---------------------------------------------------------------------------
#define GBK 32
#define GNKT 24           // 768 / 32

__global__ __launch_bounds__(512, 4) void gemm256_qkv_kernel(
    const u16* __restrict__ Af, const u16* __restrict__ Bt,
    const float* __restrict__ bias, int M,
    u16* __restrict__ o0, u16* __restrict__ o1, u16* __restrict__ o2)
{
    __shared__ __align__(16) u16 A_s[2][256 * GBK];   // 32 KiB
    __shared__ __align__(16) u16 B_s[2][128 * GBK];   // 16 KiB

    const int tid  = threadIdx.x;
    const int lane = tid & 63;
    const int w    = tid >> 6;          // 0..7
    const int wr   = w >> 1, wc = w & 1;   // 4 x 2 wave grid, wave tile 64x64

    // bijective XCD-aware swizzle (nwg = 1782)
    const int nwg = gridDim.x;
    const int qch = nwg >> 3, rch = nwg & 7;
    const int xcd = blockIdx.x & 7, idx = blockIdx.x >> 3;
    const int wg  = (xcd < rch ? xcd * (qch + 1) : rch * (qch + 1) + (xcd - rch) * qch) + idx;
    const int m0 = (wg / 18) * 256;
    const int nb = wg % 18;
    const int n0 = nb * 128;

    // staging: A tile 256x32 u16 = 1024 16B-chunks (2/thread),
    //          B tile 128x32 u16 =  512 16B-chunks (1/thread).
    // LDS dest linear; source col pre-swizzled chunk ^= ((row>>1)&3).
    const int rA0 = tid >> 2;
    const int cA0 = ((tid & 3) ^ ((rA0 >> 1) & 3)) << 3;
    const int ch1 = 512 + tid;
    const int rA1 = ch1 >> 2;
    const int cA1 = ((ch1 & 3) ^ ((rA1 >> 1) & 3)) << 3;
    const u16* pA0 = Af + (size_t)min(m0 + rA0, M - 1) * 768 + cA0;
    const u16* pA1 = Af + (size_t)min(m0 + rA1, M - 1) * 768 + cA1;
    const u16* pB  = Bt + (size_t)(n0 + rA0) * 768 + cA0;
    const int dstA0 = (w * 64) * 8;          // u16 index (lane*16B implicit)
    const int dstA1 = (512 + w * 64) * 8;
    const int dstB  = (w * 64) * 8;

    #define STAGE(buf, kk) do { \
        __builtin_amdgcn_global_load_lds(AS1(pA0 + (kk)), AS3(&A_s[buf][dstA0]), 16, 0, 0); \
        __builtin_amdgcn_global_load_lds(AS1(pA1 + (kk)), AS3(&A_s[buf][dstA1]), 16, 0, 0); \
        __builtin_amdgcn_global_load_lds(AS1(pB  + (kk)), AS3(&B_s[buf][dstB ]), 16, 0, 0); \
    } while (0)

    STAGE(0, 0);   // prologue: tile 0 in flight (3 loads/wave)

    f32x4 acc[4][4] = {};
    const int fr = lane & 15, fq = lane >> 4;
    const int sw8 = (fq ^ ((fr >> 1) & 3)) << 3;

    for (int t = 0; t < GNKT; ++t) {
        const int cur = t & 1;
        if (t < GNKT - 1) {
            STAGE(cur ^ 1, (t + 1) * GBK);
            asm volatile("s_waitcnt vmcnt(3)" ::: "memory");   // tile t landed
        } else {
            asm volatile("s_waitcnt vmcnt(0)" ::: "memory");
        }
        __builtin_amdgcn_s_barrier();

        f16x8 a[4], b[4];
        #pragma unroll
        for (int m = 0; m < 4; ++m)
            a[m] = *(const f16x8*)&A_s[cur][(wr * 64 + m * 16 + fr) * GBK + sw8];
        #pragma unroll
        for (int n = 0; n < 4; ++n)
            b[n] = *(const f16x8*)&B_s[cur][(wc * 64 + n * 16 + fr) * GBK + sw8];

        __builtin_amdgcn_s_setprio(1);
        #pragma unroll
        for (int m = 0; m < 4; ++m)
            #pragma unroll
            for (int n = 0; n < 4; ++n)
                acc[m][n] = __builtin_amdgcn_mfma_f32_16x16x32_f16(a[m], b[n], acc[m][n], 0, 0, 0);
        __builtin_amdgcn_s_setprio(0);

        if (t < GNKT - 1) __builtin_amdgcn_s_barrier();   // release buf[cur]
    }
    #undef STAGE

    // epilogue: QKV scatter. s (q/k/v) constant per block: nb/6 (128 | 768).
    const int s = nb / 6;
    u16* const dsts = (s == 0) ? o0 : (s == 1) ? o1 : o2;
    #pragma unroll
    for (int m = 0; m < 4; ++m) {
        const int growb = m0 + wr * 64 + m * 16 + fq * 4;
        #pragma unroll
        for (int j = 0; j < 4; ++j) {
            const int grow = growb + j;
            if (grow >= M) continue;
            const int bidx = grow / NTOK;
            const int ntok = grow - bidx * NTOK;
            #pragma unroll
            for (int n = 0; n < 4; ++n) {
                const int gcol = n0 + wc * 64 + n * 16 + fr;
                const float v = acc[m][n][j] + bias[gcol];
                const int rem = gcol - s * 768;
                const int h = rem >> 6, d = rem & 63;
                dsts[(size_t)((bidx * NHEADS + h) * NTOK + ntok) * 64 + d] = f2h(v);
            }
        }
    }
}

// ---------------------------------------------------------------------------
// Single-term fp16 MFMA GEMM — round-17 version; used for proj only.
// ---------------------------------------------------------------------------
template<int NBLK, bool QKV, typename OutT>
__global__ __launch_bounds__(512) void gemm_fp16_kernel(
    const u16* __restrict__ Af, const u16* __restrict__ Bt,
    const float* __restrict__ bias, int M,
    OutT* __restrict__ o0, OutT* __restrict__ o1, OutT* __restrict__ o2)
{
    __shared__ __align__(16) u16 A_s[128 * 32];
    __shared__ __align__(16) u16 B_s[128 * 32];

    const int tid  = threadIdx.x;
    const int lane = tid & 63;
    const int w    = tid >> 6;          // 0..7
    const int wr   = w >> 2, wc = w & 3;

    const int nwg = gridDim.x;
    const int qch = nwg >> 3, rch = nwg & 7;
    const int xcd = blockIdx.x & 7, idx = blockIdx.x >> 3;
    const int wg  = (xcd < rch ? xcd * (qch + 1) : rch * (qch + 1) + (xcd - rch) * qch) + idx;
    const int m0 = (wg / NBLK) * 128;
    const int n0 = (wg % NBLK) * 128;

    f32x4 acc[4][2] = {};

    const int srow   = lane >> 2;                        // 0..15
    const int sslot  = (lane & 3) ^ ((srow >> 1) & 3);   // logical 16B chunk

    for (int kt = 0; kt < 24; ++kt) {
        const int k0 = kt * 32;
        __syncthreads();

        {
            const int rb = w * 16;
            const int ra = min(m0 + rb + srow, M - 1);
            __builtin_amdgcn_global_load_lds(AS1(Af + (size_t)ra * 768 + k0 + sslot * 8),
                                             AS3(&A_s[rb * 32]), 16, 0, 0);
            __builtin_amdgcn_global_load_lds(AS1(Bt + (size_t)(n0 + rb + srow) * 768 + k0 + sslot * 8),
                                             AS3(&B_s[rb * 32]), 16, 0, 0);
        }
        __syncthreads();

        const int fr = lane & 15, fq = lane >> 4;
        const int rslot = (fq ^ ((fr >> 1) & 3)) << 3;
        f16x8 a[4], b[2];
        #pragma unroll
        for (int m = 0; m < 4; ++m)
            a[m] = *(const f16x8*)&A_s[(wr * 64 + m * 16 + fr) * 32 + rslot];
        #pragma unroll
        for (int n = 0; n < 2; ++n)
            b[n] = *(const f16x8*)&B_s[(wc * 32 + n * 16 + fr) * 32 + rslot];

        #pragma unroll
        for (int m = 0; m < 4; ++m)
            #pragma unroll
            for (int n = 0; n < 2; ++n)
                acc[m][n] = __builtin_amdgcn_mfma_f32_16x16x32_f16(a[m], b[n], acc[m][n], 0, 0, 0);
    }

    const int fr = lane & 15, fq = lane >> 4;
    #pragma unroll
    for (int m = 0; m < 4; ++m) {
        const int grow_base = m0 + wr * 64 + m * 16 + fq * 4;
        #pragma unroll
        for (int j = 0; j < 4; ++j) {
            const int grow = grow_base + j;
            if (grow >= M) continue;
            int b = 0, ntok = 0;
            if (QKV) { b = grow / NTOK; ntok = grow - b * NTOK; }
            #pragma unroll
            for (int n = 0; n < 2; ++n) {
                const int gcol = n0 + wc * 32 + n * 16 + fr;
                const float v = acc[m][n][j] + bias[gcol];
                if (QKV) {
                    const int s = gcol / 768;
                    const int rem = gcol - s * 768;
                    const int h = rem >> 6, d = rem & 63;
                    OutT* dst = (s == 0) ? o0 : (s == 1) ? o1 : o2;
                    dst[(size_t)((b * NHEADS + h) * NTOK + ntok) * 64 + d] = (OutT)f2h(v);
                } else {
                    o0[(size_t)grow * (NBLK * 128) + gcol] = (OutT)v;
                }
            }
        }
    }
}

// ---------------------------------------------------------------------------
// Depthwise conv3d + LayerNorm(64), round-18 version (proven, unchanged):
// vector-select masking; V written directly transposed with zero pad.
// ---------------------------------------------------------------------------
#define PL_PG  50                 // 32-token groups per (which,bh)
#define PL_NWG (3 * 48 * PL_PG)   // 7200
__global__ __launch_bounds__(256) void pool_ln_kernel(
    const u16* __restrict__ qr, const u16* __restrict__ kr, const u16* __restrict__ vr,
    const u16* __restrict__ wTh,
    const float* __restrict__ gq, const float* __restrict__ bq,
    const float* __restrict__ gk, const float* __restrict__ bk,
    const float* __restrict__ gv, const float* __restrict__ bv,
    u16* __restrict__ qph, u16* __restrict__ kph, u16* __restrict__ vpt)
{
    const int wg = (blockIdx.x & 7) * (PL_NWG / 8) + (blockIdx.x >> 3);
    const int which = wg / (48 * PL_PG);
    const int rem   = wg - which * (48 * PL_PG);
    const int bh    = rem / PL_PG;
    const int pg    = rem - bh * PL_PG;
    const int wv_   = threadIdx.x >> 6;
    const int lane  = threadIdx.x & 63;
    const int tg    = lane >> 3;
    const int d0    = (lane & 7) * 8;

    const int p  = pg * 32 + wv_ * 8 + tg;
    const int pc = min(p, NPOOL - 1);

    const u16*   in  = (which == 0) ? qr : (which == 1) ? kr : vr;
    const u16*   wTb = wTh + which * 27 * 64;
    const float* g   = (which == 0) ? gq : (which == 1) ? gk : gv;
    const float* bb_ = (which == 0) ? bq : (which == 1) ? bk : bv;
    const float qscale = (which == 0) ? 0.125f : 1.0f;

    const size_t inb = (size_t)bh * NTOK * 64;

    float s[8] = {};
    if (pc == 0) {
        const f16x8 t = *(const f16x8*)&in[inb + d0];
        #pragma unroll
        for (int c = 0; c < 8; ++c) s[c] = (float)t[c];
    } else {
        const int idx = pc - 1;
        const int tp = idx / (HP * WP);
        const int r2 = idx - tp * (HP * WP);
        const int hp = r2 / WP;
        const int wp = r2 - hp * WP;

        const f16x8 z8 = (f16x8)(_Float16)0.0f;
        #pragma unroll
        for (int kt = 0; kt < 3; ++kt) {
            const int it = tp + kt - 1;
            #pragma unroll
            for (int kh = 0; kh < 3; ++kh) {
                const int ih = hp * 2 + kh - 1;
                #pragma unroll
                for (int kw = 0; kw < 3; ++kw) {
                    const int iw = wp * 2 + kw - 1;
                    const int j  = kt * 9 + kh * 3 + kw;
                    const bool ok = (it >= 0) & (it < TT) & (ih >= 0) & (ih < HH) &
                                    (iw >= 0) & (iw < WW);
                    const int n   = 1 + (it * HH + ih) * WW + iw;
                    const int n_c = ok ? n : 0;            // always valid token
                    const f16x8 tv  = *(const f16x8*)&in[inb + (size_t)n_c * 64 + d0];
                    const f16x8 wv8 = *(const f16x8*)&wTb[j * 64 + d0];
                    const f16x8 ts  = ok ? tv : z8;        // zero by SELECT
                    #pragma unroll
                    for (int c = 0; c < 8; ++c)
                        s[c] = fmaf((float)wv8[c], (float)ts[c], s[c]);
                }
            }
        }
    }

    float sum = 0.f, ssq = 0.f;
    #pragma unroll
    for (int c = 0; c < 8; ++c) { sum += s[c]; ssq += s[c] * s[c]; }
    #pragma unroll
    for (int off = 1; off < 8; off <<= 1) {
        sum += __shfl_xor(sum, off);
        ssq += __shfl_xor(ssq, off);
    }
    const float mu  = sum * (1.f / 64.f);
    const float var = ssq * (1.f / 64.f) - mu * mu;
    const float rs  = rsqrtf(var + 1e-5f);

    float g8[8], b8[8];
    {
        const float4 g0 = *(const float4*)&g[d0];
        const float4 g1 = *(const float4*)&g[d0 + 4];
        const float4 b0 = *(const float4*)&bb_[d0];
        const float4 b1 = *(const float4*)&bb_[d0 + 4];
        g8[0]=g0.x; g8[1]=g0.y; g8[2]=g0.z; g8[3]=g0.w;
        g8[4]=g1.x; g8[5]=g1.y; g8[6]=g1.z; g8[7]=g1.w;
        b8[0]=b0.x; b8[1]=b0.y; b8[2]=b0.z; b8[3]=b0.w;
        b8[4]=b1.x; b8[5]=b1.y; b8[6]=b1.z; b8[7]=b1.w;
    }

    u16 oo[8];
    #pragma unroll
    for (int c = 0; c < 8; ++c)
        oo[c] = f2h(((s[c] - mu) * rs * g8[c] + b8[c]) * qscale);

    if (which == 2) {
        u16* base = vpt + (size_t)bh * 64 * NPOOLP + p;
        if (p < NPOOL) {
            #pragma unroll
            for (int c = 0; c < 8; ++c)
                base[(size_t)(d0 + c) * NPOOLP] = oo[c];
        } else {
            #pragma unroll
            for (int c = 0; c < 8; ++c)
                base[(size_t)(d0 + c) * NPOOLP] = 0;
        }
    } else if (p < NPOOL) {
        u16* out = (which == 0) ? qph : kph;
        u16* dst = &out[((size_t)bh * NPOOL + p) * 64 + d0];
        *(ushort4*)&dst[0] = *(ushort4*)&oo[0];
        *(ushort4*)&dst[4] = *(ushort4*)&oo[4];
    }
}

// ---------------------------------------------------------------------------
// Round-27 flash attention (passing): single-pass + double-buffered K/V
// prefetch with __syncthreads-only synchronization.  UNCHANGED.
// ---------------------------------------------------------------------------
__global__ __launch_bounds__(256) void flash_attn_fp16_kernel(
    const u16* __restrict__ qh, const u16* __restrict__ kh,
    const u16* __restrict__ vt, u16* __restrict__ aoh)
{
    __shared__ __align__(16) u16 K_s[2][64 * 64];
    __shared__ __align__(16) u16 V_s[2][64 * 64];
    __shared__ __align__(16) u16 P_s[4][16 * 64];

    const int bh = blockIdx.y;
    const int q0 = blockIdx.x * 64;
    const int tid = threadIdx.x;
    const int w = tid >> 6, lane = tid & 63;
    const int fr = lane & 15, fq = lane >> 4;
    const int l8 = lane >> 3;
    const int sw = 8 * ((lane & 7) ^ l8);

    const size_t hb  = (size_t)bh * NPOOL * 64;
    const size_t vtb = (size_t)bh * 64 * NPOOLP;

    f16x8 qf_[2];
    {
        const int row = min(q0 + w * 16 + fr, NPOOL - 1);
        #pragma unroll
        for (int half = 0; half < 2; ++half)
            qf_[half] = *(const f16x8*)&qh[hb + (size_t)row * 64 + half * 32 + fq * 8];
    }

    f16x8 ones;
    #pragma unroll
    for (int i = 0; i < 8; ++i) ones[i] = (_Float16)1.0f;

    f32x4 acc[4] = {};
    f32x4 l_acc = {};

    #define STAGEKV(buf, kt) do { \
        _Pragma("unroll") \
        for (int i = 0; i < 2; ++i) { \
            const int rb = w * 16 + i * 8; \
            const int r  = rb + l8; \
            const int gk = min((kt) * 64 + r, NPOOL - 1); \
            __builtin_amdgcn_global_load_lds(AS1(kh + hb + (size_t)gk * 64 + sw), \
                                             AS3(&K_s[buf][rb * 64]), 16, 0, 0); \
            __builtin_amdgcn_global_load_lds(AS1(vt + vtb + (size_t)r * NPOOLP + (kt) * 64 + sw), \
                                             AS3(&V_s[buf][rb * 64]), 16, 0, 0); \
        } \
    } while (0)

    #define LDSW(buf, row, colbyte) \
        (*(const f16x8*)((const char*)(buf) + ((row) * 128 + ((colbyte) ^ (((row) & 7) << 4)))))

    STAGEKV(0, 0);     // tile 0 in flight
    __syncthreads();   // tile 0 landed (full drain), waves synced

    for (int kt = 0; kt < 25; ++kt) {
        const int cur = kt & 1;
        if (kt < 24) STAGEKV(cur ^ 1, kt + 1);

        const int k0 = kt * 64;
        f32x4 sv[4];
        #pragma unroll
        for (int nf = 0; nf < 4; ++nf) {
            const int krow = nf * 16 + fr;
            const f16x8 kf0 = LDSW(&K_s[cur][0], krow, fq * 16);
            const f16x8 kf1 = LDSW(&K_s[cur][0], krow, 64 + fq * 16);
            f32x4 s = {};
            s = __builtin_amdgcn_mfma_f32_16x16x32_f16(qf_[0], kf0, s, 0, 0, 0);
            s = __builtin_amdgcn_mfma_f32_16x16x32_f16(qf_[1], kf1, s, 0, 0, 0);
            sv[nf] = s;
        }

        #pragma unroll
        for (int nf = 0; nf < 4; ++nf) {
            const bool valid = (k0 + nf * 16 + fr) < NPOOL;
            #pragma unroll
            for (int j = 0; j < 4; ++j) {
                const float p = valid ? __expf(sv[nf][j]) : 0.f;
                const int row = fq * 4 + j;
                const int bo  = row * 128 + ((nf * 32 + fr * 2) ^ ((row & 7) << 4));
                *(u16*)((char*)&P_s[w][0] + bo) = f2h(p);
            }
        }
        __builtin_amdgcn_sched_barrier(0);

        const f16x8 pa0 = LDSW(&P_s[w][0], fr, fq * 16);
        const f16x8 pa1 = LDSW(&P_s[w][0], fr, 64 + fq * 16);
        l_acc = __builtin_amdgcn_mfma_f32_16x16x32_f16(pa0, ones, l_acc, 0, 0, 0);
        l_acc = __builtin_amdgcn_mfma_f32_16x16x32_f16(pa1, ones, l_acc, 0, 0, 0);
        #pragma unroll
        for (int df = 0; df < 4; ++df) {
            const int vrow = df * 16 + fr;
            const f16x8 v0 = LDSW(&V_s[cur][0], vrow, fq * 16);
            const f16x8 v1 = LDSW(&V_s[cur][0], vrow, 64 + fq * 16);
            acc[df] = __builtin_amdgcn_mfma_f32_16x16x32_f16(pa0, v0, acc[df], 0, 0, 0);
            acc[df] = __builtin_amdgcn_mfma_f32_16x16x32_f16(pa1, v1, acc[df], 0, 0, 0);
        }

        __syncthreads();
    }
    #undef LDSW
    #undef STAGEKV

    const int b = bh / NHEADS, h = bh % NHEADS;
    #pragma unroll
    for (int j = 0; j < 4; ++j) {
        const int q = q0 + w * 16 + fq * 4 + j;
        if (q >= NPOOL) continue;
        const float inv = 1.f / l_acc[j];
        u16* dst = &aoh[((size_t)(b * NPOOL + q)) * 768 + h * 64];
        #pragma unroll
        for (int df = 0; df < 4; ++df)
            dst[df * 16 + fr] = f2h(acc[df][j] * inv);
    }
}

// ---------------------------------------------------------------------------
extern "C" void kernel_launch(void* const* d_in, const int* in_sizes, int n_in,
                              void* d_out, int out_size, void* d_ws, size_t ws_size,
                              hipStream_t stream)
{
    const float* x      = (const float*)d_in[0];
    const float* qkv_w  = (const float*)d_in[1];
    const float* qkv_b  = (const float*)d_in[2];
    const float* proj_w = (const float*)d_in[3];
    const float* proj_b = (const float*)d_in[4];
    const float* wq     = (const float*)d_in[5];
    const float* wk     = (const float*)d_in[6];
    const float* wv     = (const float*)d_in[7];
    const float* gq     = (const float*)d_in[8];
    const float* bq     = (const float*)d_in[9];
    const float* gk     = (const float*)d_in[10];
    const float* bk     = (const float*)d_in[11];
    const float* gv     = (const float*)d_in[12];
    const float* bv     = (const float*)d_in[13];

    const size_t RAW  = (size_t)BB * NHEADS * NTOK * 64;   // 19,270,656 (= M*768)
    const size_t PLD  = (size_t)BB * NHEADS * NPOOL * 64;
    const size_t VTSZ = (size_t)BB * NHEADS * 64 * NPOOLP;

    u16* q_raw = (u16*)d_ws;          // fp16
    u16* k_raw = q_raw + RAW;
    u16* v_raw = k_raw + RAW;
    u16* xh    = v_raw + RAW;
    u16* qph   = xh + RAW;
    u16* kph   = qph + PLD;
    u16* vpb   = kph + PLD;          // unused (layout stability)
    u16* vpt   = vpb + PLD;
    u16* wth   = vpt + VTSZ;
    u16* pwth  = wth + (size_t)2304 * 768;
    u16* wTh   = pwth + (size_t)768 * 768;   // 3*27*64 fp16
    u16* aoh   = q_raw;               // q_raw dead after pool_ln

    cvt_f32_f16_kernel<<<2048, 256, 0, stream>>>(x, xh, (int)(RAW / 4));

    // merged prep: qkv_w transpose (1728) + proj_w transpose (576) + conv wt (3)
    prep_kernel<<<dim3(2307), 256, 0, stream>>>(
        qkv_w, proj_w, wq, wk, wv, wth, pwth, wTh);

    // 256x128 tiles: ceil(25092/256)=99 M-tiles x 18 N-tiles = 1782 blocks
    gemm256_qkv_kernel<<<dim3(99 * 18), 512, 0, stream>>>(
        xh, wth, qkv_b, BB * NTOK, q_raw, k_raw, v_raw);

    pool_ln_kernel<<<dim3(PL_NWG), 256, 0, stream>>>(
        q_raw, k_raw, v_raw, wTh, gq, bq, gk, bk, gv, bv,
        qph, kph, vpt);

    // single-pass attention: 25 q-tiles x 48 heads, fp16 out, no combine
    flash_attn_fp16_kernel<<<dim3(25, 48), 256, 0, stream>>>(
        qph, kph, vpt, aoh);

    gemm_fp16_kernel<6, false, float><<<dim3(50 * 6), 512, 0, stream>>>(
        aoh, pwth, proj_b, BB * NPOOL, (float*)d_out, nullptr, nullptr);
}

// Round 11
// 288.050 us; speedup vs baseline: 1.0979x; 1.0133x over previous
//
#include <hip/hip_runtime.h>
#include <hip/hip_bf16.h>

#define BB      4
#define NTOK    6273      // 1 + 8*28*28
#define NPOOL   1569      // 1 + 8*14*14
#define NPOOLP  1600      // padded kv length (25 * 64)
#define NHEADS  12
#define TT      8
#define HH      28
#define WW      28
#define HP      14
#define WP      14

typedef __attribute__((ext_vector_type(8))) _Float16 f16x8;
typedef __attribute__((ext_vector_type(4))) float f32x4;
typedef unsigned short u16;

#define AS1(p) ((const __attribute__((address_space(1))) void*)(p))
#define AS3(p) ((__attribute__((address_space(3))) void*)(p))

static __device__ __forceinline__ u16 f2h(float x) {
    union { _Float16 h; u16 u; } c; c.h = (_Float16)x; return c.u;
}
static __device__ __forceinline__ float h2f(u16 u) {
    union { u16 u; _Float16 h; } c; c.u = u; return (float)c.h;
}

// ---------------------------------------------------------------------------
// Round-30 merged prep: ONE launch covering all pre-GEMM data prep.
//   blocks [0, 2048)        : x fp32 -> fp16 flat convert (grid-stride)
//   blocks [2048, 3776)     : transpose_cvt qkv_w  (768x2304 -> wth)
//   blocks [3776, 4352)     : transpose_cvt proj_w (768x768  -> pwth)
//   blocks [4352, 4355)     : wt_transpose  wq/wk/wv -> wTh
// Bodies verbatim from the proven kernels; only dispatch is new.  Extends
// round-29's measured +4us fusion: one fewer launch, and the small transpose
// traffic rides in cvt's BW shadow instead of serializing behind it.
// ---------------------------------------------------------------------------
__global__ __launch_bounds__(256) void prep_kernel(
    const float* __restrict__ x, u16* __restrict__ xh, int n4,
    const float* __restrict__ qkv_w, const float* __restrict__ proj_w,
    const float* __restrict__ wq, const float* __restrict__ wk,
    const float* __restrict__ wv,
    u16* __restrict__ wth, u16* __restrict__ pwth, u16* __restrict__ wTh)
{
    __shared__ float tile[32][33];
    const int b = blockIdx.x;

    if (b < 2048) {
        int i = b * 256 + threadIdx.x;
        const int stride = 2048 * 256;
        for (; i < n4; i += stride) {
            const float4 v = ((const float4*)x)[i];
            ushort4 o;
            o.x = f2h(v.x); o.y = f2h(v.y); o.z = f2h(v.z); o.w = f2h(v.w);
            ((ushort4*)xh)[i] = o;
        }
        return;
    }

    const int tx = threadIdx.x & 31, ty = threadIdx.x >> 5;   // (32,8) layout
    if (b < 4352) {
        const float* W; u16* t; int K, N, n0, k0;
        if (b < 3776) {
            const int ib = b - 2048;
            W = qkv_w; t = wth; K = 768; N = 2304;
            n0 = (ib % 72) * 32; k0 = (ib / 72) * 32;
        } else {
            const int ib = b - 3776;
            W = proj_w; t = pwth; K = 768; N = 768;
            n0 = (ib % 24) * 32; k0 = (ib / 24) * 32;
        }
        #pragma unroll
        for (int i = 0; i < 4; ++i)
            tile[ty + i * 8][tx] = W[(size_t)(k0 + ty + i * 8) * N + n0 + tx];
        __syncthreads();
        #pragma unroll
        for (int i = 0; i < 4; ++i) {
            const int n = n0 + ty + i * 8;
            t[(size_t)n * K + k0 + tx] = f2h(tile[tx][ty + i * 8]);
        }
    } else {
        const int which = b - 4352;
        const float* w = (which == 0) ? wq : (which == 1) ? wk : wv;
        u16* o = wTh + which * 27 * 64;
        for (int i = threadIdx.x; i < 27 * 64; i += 256) {
            const int j = i >> 6, d = i & 63;
            o[j * 64 + d] = f2h(w[d * 27 + j]);
        }
    }
}

// ---------------------------------------------------------------------------
// QKV GEMM: round-21 version, FROZEN (121.5us, 0 bank conflicts, VGPR 56).
// ---------------------------------------------------------------------------
#define GBK 32
#define GNKT 24           // 768 / 32

__global__ __launch_bounds__(512, 4) void gemm256_qkv_kernel(
    const u16* __restrict__ Af, const u16* __restrict__ Bt,
    const float* __restrict__ bias, int M,
    u16* __restrict__ o0, u16* __restrict__ o1, u16* __restrict__ o2)
{
    __shared__ __align__(16) u16 A_s[2][256 * GBK];   // 32 KiB
    __shared__ __align__(16) u16 B_s[2][128 * GBK];   // 16 KiB

    const int tid  = threadIdx.x;
    const int lane = tid & 63;
    const int w    = tid >> 6;          // 0..7
    const int wr   = w >> 1, wc = w & 1;   // 4 x 2 wave grid, wave tile 64x64

    // bijective XCD-aware swizzle (nwg = 1782)
    const int nwg = gridDim.x;
    const int qch = nwg >> 3, rch = nwg & 7;
    const int xcd = blockIdx.x & 7, idx = blockIdx.x >> 3;
    const int wg  = (xcd < rch ? xcd * (qch + 1) : rch * (qch + 1) + (xcd - rch) * qch) + idx;
    const int m0 = (wg / 18) * 256;
    const int nb = wg % 18;
    const int n0 = nb * 128;

    // staging: A tile 256x32 u16 = 1024 16B-chunks (2/thread),
    //          B tile 128x32 u16 =  512 16B-chunks (1/thread).
    // LDS dest linear; source col pre-swizzled chunk ^= ((row>>1)&3).
    const int rA0 = tid >> 2;
    const int cA0 = ((tid & 3) ^ ((rA0 >> 1) & 3)) << 3;
    const int ch1 = 512 + tid;
    const int rA1 = ch1 >> 2;
    const int cA1 = ((ch1 & 3) ^ ((rA1 >> 1) & 3)) << 3;
    const u16* pA0 = Af + (size_t)min(m0 + rA0, M - 1) * 768 + cA0;
    const u16* pA1 = Af + (size_t)min(m0 + rA1, M - 1) * 768 + cA1;
    const u16* pB  = Bt + (size_t)(n0 + rA0) * 768 + cA0;
    const int dstA0 = (w * 64) * 8;          // u16 index (lane*16B implicit)
    const int dstA1 = (512 + w * 64) * 8;
    const int dstB  = (w * 64) * 8;

    #define STAGE(buf, kk) do { \
        __builtin_amdgcn_global_load_lds(AS1(pA0 + (kk)), AS3(&A_s[buf][dstA0]), 16, 0, 0); \
        __builtin_amdgcn_global_load_lds(AS1(pA1 + (kk)), AS3(&A_s[buf][dstA1]), 16, 0, 0); \
        __builtin_amdgcn_global_load_lds(AS1(pB  + (kk)), AS3(&B_s[buf][dstB ]), 16, 0, 0); \
    } while (0)

    STAGE(0, 0);   // prologue: tile 0 in flight (3 loads/wave)

    f32x4 acc[4][4] = {};
    const int fr = lane & 15, fq = lane >> 4;
    const int sw8 = (fq ^ ((fr >> 1) & 3)) << 3;

    for (int t = 0; t < GNKT; ++t) {
        const int cur = t & 1;
        if (t < GNKT - 1) {
            STAGE(cur ^ 1, (t + 1) * GBK);
            asm volatile("s_waitcnt vmcnt(3)" ::: "memory");   // tile t landed
        } else {
            asm volatile("s_waitcnt vmcnt(0)" ::: "memory");
        }
        __builtin_amdgcn_s_barrier();

        f16x8 a[4], b[4];
        #pragma unroll
        for (int m = 0; m < 4; ++m)
            a[m] = *(const f16x8*)&A_s[cur][(wr * 64 + m * 16 + fr) * GBK + sw8];
        #pragma unroll
        for (int n = 0; n < 4; ++n)
            b[n] = *(const f16x8*)&B_s[cur][(wc * 64 + n * 16 + fr) * GBK + sw8];

        __builtin_amdgcn_s_setprio(1);
        #pragma unroll
        for (int m = 0; m < 4; ++m)
            #pragma unroll
            for (int n = 0; n < 4; ++n)
                acc[m][n] = __builtin_amdgcn_mfma_f32_16x16x32_f16(a[m], b[n], acc[m][n], 0, 0, 0);
        __builtin_amdgcn_s_setprio(0);

        if (t < GNKT - 1) __builtin_amdgcn_s_barrier();   // release buf[cur]
    }
    #undef STAGE

    // epilogue: QKV scatter. s (q/k/v) constant per block: nb/6 (128 | 768).
    const int s = nb / 6;
    u16* const dsts = (s == 0) ? o0 : (s == 1) ? o1 : o2;
    #pragma unroll
    for (int m = 0; m < 4; ++m) {
        const int growb = m0 + wr * 64 + m * 16 + fq * 4;
        #pragma unroll
        for (int j = 0; j < 4; ++j) {
            const int grow = growb + j;
            if (grow >= M) continue;
            const int bidx = grow / NTOK;
            const int ntok = grow - bidx * NTOK;
            #pragma unroll
            for (int n = 0; n < 4; ++n) {
                const int gcol = n0 + wc * 64 + n * 16 + fr;
                const float v = acc[m][n][j] + bias[gcol];
                const int rem = gcol - s * 768;
                const int h = rem >> 6, d = rem & 63;
                dsts[(size_t)((bidx * NHEADS + h) * NTOK + ntok) * 64 + d] = f2h(v);
            }
        }
    }
}

// ---------------------------------------------------------------------------
// Single-term fp16 MFMA GEMM — round-17 version; used for proj only.
// ---------------------------------------------------------------------------
template<int NBLK, bool QKV, typename OutT>
__global__ __launch_bounds__(512) void gemm_fp16_kernel(
    const u16* __restrict__ Af, const u16* __restrict__ Bt,
    const float* __restrict__ bias, int M,
    OutT* __restrict__ o0, OutT* __restrict__ o1, OutT* __restrict__ o2)
{
    __shared__ __align__(16) u16 A_s[128 * 32];
    __shared__ __align__(16) u16 B_s[128 * 32];

    const int tid  = threadIdx.x;
    const int lane = tid & 63;
    const int w    = tid >> 6;          // 0..7
    const int wr   = w >> 2, wc = w & 3;

    const int nwg = gridDim.x;
    const int qch = nwg >> 3, rch = nwg & 7;
    const int xcd = blockIdx.x & 7, idx = blockIdx.x >> 3;
    const int wg  = (xcd < rch ? xcd * (qch + 1) : rch * (qch + 1) + (xcd - rch) * qch) + idx;
    const int m0 = (wg / NBLK) * 128;
    const int n0 = (wg % NBLK) * 128;

    f32x4 acc[4][2] = {};

    const int srow   = lane >> 2;                        // 0..15
    const int sslot  = (lane & 3) ^ ((srow >> 1) & 3);   // logical 16B chunk

    for (int kt = 0; kt < 24; ++kt) {
        const int k0 = kt * 32;
        __syncthreads();

        {
            const int rb = w * 16;
            const int ra = min(m0 + rb + srow, M - 1);
            __builtin_amdgcn_global_load_lds(AS1(Af + (size_t)ra * 768 + k0 + sslot * 8),
                                             AS3(&A_s[rb * 32]), 16, 0, 0);
            __builtin_amdgcn_global_load_lds(AS1(Bt + (size_t)(n0 + rb + srow) * 768 + k0 + sslot * 8),
                                             AS3(&B_s[rb * 32]), 16, 0, 0);
        }
        __syncthreads();

        const int fr = lane & 15, fq = lane >> 4;
        const int rslot = (fq ^ ((fr >> 1) & 3)) << 3;
        f16x8 a[4], b[2];
        #pragma unroll
        for (int m = 0; m < 4; ++m)
            a[m] = *(const f16x8*)&A_s[(wr * 64 + m * 16 + fr) * 32 + rslot];
        #pragma unroll
        for (int n = 0; n < 2; ++n)
            b[n] = *(const f16x8*)&B_s[(wc * 32 + n * 16 + fr) * 32 + rslot];

        #pragma unroll
        for (int m = 0; m < 4; ++m)
            #pragma unroll
            for (int n = 0; n < 2; ++n)
                acc[m][n] = __builtin_amdgcn_mfma_f32_16x16x32_f16(a[m], b[n], acc[m][n], 0, 0, 0);
    }

    const int fr = lane & 15, fq = lane >> 4;
    #pragma unroll
    for (int m = 0; m < 4; ++m) {
        const int grow_base = m0 + wr * 64 + m * 16 + fq * 4;
        #pragma unroll
        for (int j = 0; j < 4; ++j) {
            const int grow = grow_base + j;
            if (grow >= M) continue;
            int b = 0, ntok = 0;
            if (QKV) { b = grow / NTOK; ntok = grow - b * NTOK; }
            #pragma unroll
            for (int n = 0; n < 2; ++n) {
                const int gcol = n0 + wc * 32 + n * 16 + fr;
                const float v = acc[m][n][j] + bias[gcol];
                if (QKV) {
                    const int s = gcol / 768;
                    const int rem = gcol - s * 768;
                    const int h = rem >> 6, d = rem & 63;
                    OutT* dst = (s == 0) ? o0 : (s == 1) ? o1 : o2;
                    dst[(size_t)((b * NHEADS + h) * NTOK + ntok) * 64 + d] = (OutT)f2h(v);
                } else {
                    o0[(size_t)grow * (NBLK * 128) + gcol] = (OutT)v;
                }
            }
        }
    }
}

// ---------------------------------------------------------------------------
// Depthwise conv3d + LayerNorm(64), round-18 version (proven, unchanged):
// vector-select masking; V written directly transposed with zero pad.
// ---------------------------------------------------------------------------
#define PL_PG  50                 // 32-token groups per (which,bh)
#define PL_NWG (3 * 48 * PL_PG)   // 7200
__global__ __launch_bounds__(256) void pool_ln_kernel(
    const u16* __restrict__ qr, const u16* __restrict__ kr, const u16* __restrict__ vr,
    const u16* __restrict__ wTh,
    const float* __restrict__ gq, const float* __restrict__ bq,
    const float* __restrict__ gk, const float* __restrict__ bk,
    const float* __restrict__ gv, const float* __restrict__ bv,
    u16* __restrict__ qph, u16* __restrict__ kph, u16* __restrict__ vpt)
{
    const int wg = (blockIdx.x & 7) * (PL_NWG / 8) + (blockIdx.x >> 3);
    const int which = wg / (48 * PL_PG);
    const int rem   = wg - which * (48 * PL_PG);
    const int bh    = rem / PL_PG;
    const int pg    = rem - bh * PL_PG;
    const int wv_   = threadIdx.x >> 6;
    const int lane  = threadIdx.x & 63;
    const int tg    = lane >> 3;
    const int d0    = (lane & 7) * 8;

    const int p  = pg * 32 + wv_ * 8 + tg;
    const int pc = min(p, NPOOL - 1);

    const u16*   in  = (which == 0) ? qr : (which == 1) ? kr : vr;
    const u16*   wTb = wTh + which * 27 * 64;
    const float* g   = (which == 0) ? gq : (which == 1) ? gk : gv;
    const float* bb_ = (which == 0) ? bq : (which == 1) ? bk : bv;
    const float qscale = (which == 0) ? 0.125f : 1.0f;

    const size_t inb = (size_t)bh * NTOK * 64;

    float s[8] = {};
    if (pc == 0) {
        const f16x8 t = *(const f16x8*)&in[inb + d0];
        #pragma unroll
        for (int c = 0; c < 8; ++c) s[c] = (float)t[c];
    } else {
        const int idx = pc - 1;
        const int tp = idx / (HP * WP);
        const int r2 = idx - tp * (HP * WP);
        const int hp = r2 / WP;
        const int wp = r2 - hp * WP;

        const f16x8 z8 = (f16x8)(_Float16)0.0f;
        #pragma unroll
        for (int kt = 0; kt < 3; ++kt) {
            const int it = tp + kt - 1;
            #pragma unroll
            for (int kh = 0; kh < 3; ++kh) {
                const int ih = hp * 2 + kh - 1;
                #pragma unroll
                for (int kw = 0; kw < 3; ++kw) {
                    const int iw = wp * 2 + kw - 1;
                    const int j  = kt * 9 + kh * 3 + kw;
                    const bool ok = (it >= 0) & (it < TT) & (ih >= 0) & (ih < HH) &
                                    (iw >= 0) & (iw < WW);
                    const int n   = 1 + (it * HH + ih) * WW + iw;
                    const int n_c = ok ? n : 0;            // always valid token
                    const f16x8 tv  = *(const f16x8*)&in[inb + (size_t)n_c * 64 + d0];
                    const f16x8 wv8 = *(const f16x8*)&wTb[j * 64 + d0];
                    const f16x8 ts  = ok ? tv : z8;        // zero by SELECT
                    #pragma unroll
                    for (int c = 0; c < 8; ++c)
                        s[c] = fmaf((float)wv8[c], (float)ts[c], s[c]);
                }
            }
        }
    }

    float sum = 0.f, ssq = 0.f;
    #pragma unroll
    for (int c = 0; c < 8; ++c) { sum += s[c]; ssq += s[c] * s[c]; }
    #pragma unroll
    for (int off = 1; off < 8; off <<= 1) {
        sum += __shfl_xor(sum, off);
        ssq += __shfl_xor(ssq, off);
    }
    const float mu  = sum * (1.f / 64.f);
    const float var = ssq * (1.f / 64.f) - mu * mu;
    const float rs  = rsqrtf(var + 1e-5f);

    float g8[8], b8[8];
    {
        const float4 g0 = *(const float4*)&g[d0];
        const float4 g1 = *(const float4*)&g[d0 + 4];
        const float4 b0 = *(const float4*)&bb_[d0];
        const float4 b1 = *(const float4*)&bb_[d0 + 4];
        g8[0]=g0.x; g8[1]=g0.y; g8[2]=g0.z; g8[3]=g0.w;
        g8[4]=g1.x; g8[5]=g1.y; g8[6]=g1.z; g8[7]=g1.w;
        b8[0]=b0.x; b8[1]=b0.y; b8[2]=b0.z; b8[3]=b0.w;
        b8[4]=b1.x; b8[5]=b1.y; b8[6]=b1.z; b8[7]=b1.w;
    }

    u16 oo[8];
    #pragma unroll
    for (int c = 0; c < 8; ++c)
        oo[c] = f2h(((s[c] - mu) * rs * g8[c] + b8[c]) * qscale);

    if (which == 2) {
        u16* base = vpt + (size_t)bh * 64 * NPOOLP + p;
        if (p < NPOOL) {
            #pragma unroll
            for (int c = 0; c < 8; ++c)
                base[(size_t)(d0 + c) * NPOOLP] = oo[c];
        } else {
            #pragma unroll
            for (int c = 0; c < 8; ++c)
                base[(size_t)(d0 + c) * NPOOLP] = 0;
        }
    } else if (p < NPOOL) {
        u16* out = (which == 0) ? qph : kph;
        u16* dst = &out[((size_t)bh * NPOOL + p) * 64 + d0];
        *(ushort4*)&dst[0] = *(ushort4*)&oo[0];
        *(ushort4*)&dst[4] = *(ushort4*)&oo[4];
    }
}

// ---------------------------------------------------------------------------
// Round-27 flash attention (passing): single-pass + double-buffered K/V
// prefetch with __syncthreads-only synchronization.  UNCHANGED.
// ---------------------------------------------------------------------------
__global__ __launch_bounds__(256) void flash_attn_fp16_kernel(
    const u16* __restrict__ qh, const u16* __restrict__ kh,
    const u16* __restrict__ vt, u16* __restrict__ aoh)
{
    __shared__ __align__(16) u16 K_s[2][64 * 64];
    __shared__ __align__(16) u16 V_s[2][64 * 64];
    __shared__ __align__(16) u16 P_s[4][16 * 64];

    const int bh = blockIdx.y;
    const int q0 = blockIdx.x * 64;
    const int tid = threadIdx.x;
    const int w = tid >> 6, lane = tid & 63;
    const int fr = lane & 15, fq = lane >> 4;
    const int l8 = lane >> 3;
    const int sw = 8 * ((lane & 7) ^ l8);

    const size_t hb  = (size_t)bh * NPOOL * 64;
    const size_t vtb = (size_t)bh * 64 * NPOOLP;

    f16x8 qf_[2];
    {
        const int row = min(q0 + w * 16 + fr, NPOOL - 1);
        #pragma unroll
        for (int half = 0; half < 2; ++half)
            qf_[half] = *(const f16x8*)&qh[hb + (size_t)row * 64 + half * 32 + fq * 8];
    }

    f16x8 ones;
    #pragma unroll
    for (int i = 0; i < 8; ++i) ones[i] = (_Float16)1.0f;

    f32x4 acc[4] = {};
    f32x4 l_acc = {};

    #define STAGEKV(buf, kt) do { \
        _Pragma("unroll") \
        for (int i = 0; i < 2; ++i) { \
            const int rb = w * 16 + i * 8; \
            const int r  = rb + l8; \
            const int gk = min((kt) * 64 + r, NPOOL - 1); \
            __builtin_amdgcn_global_load_lds(AS1(kh + hb + (size_t)gk * 64 + sw), \
                                             AS3(&K_s[buf][rb * 64]), 16, 0, 0); \
            __builtin_amdgcn_global_load_lds(AS1(vt + vtb + (size_t)r * NPOOLP + (kt) * 64 + sw), \
                                             AS3(&V_s[buf][rb * 64]), 16, 0, 0); \
        } \
    } while (0)

    #define LDSW(buf, row, colbyte) \
        (*(const f16x8*)((const char*)(buf) + ((row) * 128 + ((colbyte) ^ (((row) & 7) << 4)))))

    STAGEKV(0, 0);     // tile 0 in flight
    __syncthreads();   // tile 0 landed (full drain), waves synced

    for (int kt = 0; kt < 25; ++kt) {
        const int cur = kt & 1;
        if (kt < 24) STAGEKV(cur ^ 1, kt + 1);

        const int k0 = kt * 64;
        f32x4 sv[4];
        #pragma unroll
        for (int nf = 0; nf < 4; ++nf) {
            const int krow = nf * 16 + fr;
            const f16x8 kf0 = LDSW(&K_s[cur][0], krow, fq * 16);
            const f16x8 kf1 = LDSW(&K_s[cur][0], krow, 64 + fq * 16);
            f32x4 s = {};
            s = __builtin_amdgcn_mfma_f32_16x16x32_f16(qf_[0], kf0, s, 0, 0, 0);
            s = __builtin_amdgcn_mfma_f32_16x16x32_f16(qf_[1], kf1, s, 0, 0, 0);
            sv[nf] = s;
        }

        #pragma unroll
        for (int nf = 0; nf < 4; ++nf) {
            const bool valid = (k0 + nf * 16 + fr) < NPOOL;
            #pragma unroll
            for (int j = 0; j < 4; ++j) {
                const float p = valid ? __expf(sv[nf][j]) : 0.f;
                const int row = fq * 4 + j;
                const int bo  = row * 128 + ((nf * 32 + fr * 2) ^ ((row & 7) << 4));
                *(u16*)((char*)&P_s[w][0] + bo) = f2h(p);
            }
        }
        __builtin_amdgcn_sched_barrier(0);

        const f16x8 pa0 = LDSW(&P_s[w][0], fr, fq * 16);
        const f16x8 pa1 = LDSW(&P_s[w][0], fr, 64 + fq * 16);
        l_acc = __builtin_amdgcn_mfma_f32_16x16x32_f16(pa0, ones, l_acc, 0, 0, 0);
        l_acc = __builtin_amdgcn_mfma_f32_16x16x32_f16(pa1, ones, l_acc, 0, 0, 0);
        #pragma unroll
        for (int df = 0; df < 4; ++df) {
            const int vrow = df * 16 + fr;
            const f16x8 v0 = LDSW(&V_s[cur][0], vrow, fq * 16);
            const f16x8 v1 = LDSW(&V_s[cur][0], vrow, 64 + fq * 16);
            acc[df] = __builtin_amdgcn_mfma_f32_16x16x32_f16(pa0, v0, acc[df], 0, 0, 0);
            acc[df] = __builtin_amdgcn_mfma_f32_16x16x32_f16(pa1, v1, acc[df], 0, 0, 0);
        }

        __syncthreads();
    }
    #undef LDSW
    #undef STAGEKV

    const int b = bh / NHEADS, h = bh % NHEADS;
    #pragma unroll
    for (int j = 0; j < 4; ++j) {
        const int q = q0 + w * 16 + fq * 4 + j;
        if (q >= NPOOL) continue;
        const float inv = 1.f / l_acc[j];
        u16* dst = &aoh[((size_t)(b * NPOOL + q)) * 768 + h * 64];
        #pragma unroll
        for (int df = 0; df < 4; ++df)
            dst[df * 16 + fr] = f2h(acc[df][j] * inv);
    }
}

// ---------------------------------------------------------------------------
extern "C" void kernel_launch(void* const* d_in, const int* in_sizes, int n_in,
                              void* d_out, int out_size, void* d_ws, size_t ws_size,
                              hipStream_t stream)
{
    const float* x      = (const float*)d_in[0];
    const float* qkv_w  = (const float*)d_in[1];
    const float* qkv_b  = (const float*)d_in[2];
    const float* proj_w = (const float*)d_in[3];
    const float* proj_b = (const float*)d_in[4];
    const float* wq     = (const float*)d_in[5];
    const float* wk     = (const float*)d_in[6];
    const float* wv     = (const float*)d_in[7];
    const float* gq     = (const float*)d_in[8];
    const float* bq     = (const float*)d_in[9];
    const float* gk     = (const float*)d_in[10];
    const float* bk     = (const float*)d_in[11];
    const float* gv     = (const float*)d_in[12];
    const float* bv     = (const float*)d_in[13];

    const size_t RAW  = (size_t)BB * NHEADS * NTOK * 64;   // 19,270,656 (= M*768)
    const size_t PLD  = (size_t)BB * NHEADS * NPOOL * 64;
    const size_t VTSZ = (size_t)BB * NHEADS * 64 * NPOOLP;

    u16* q_raw = (u16*)d_ws;          // fp16
    u16* k_raw = q_raw + RAW;
    u16* v_raw = k_raw + RAW;
    u16* xh    = v_raw + RAW;
    u16* qph   = xh + RAW;
    u16* kph   = qph + PLD;
    u16* vpb   = kph + PLD;          // unused (layout stability)
    u16* vpt   = vpb + PLD;
    u16* wth   = vpt + VTSZ;
    u16* pwth  = wth + (size_t)2304 * 768;
    u16* wTh   = pwth + (size_t)768 * 768;   // 3*27*64 fp16
    u16* aoh   = q_raw;               // q_raw dead after pool_ln

    // merged prep: x cvt (2048) + qkv_w transpose (1728) + proj_w (576) + wt (3)
    prep_kernel<<<dim3(4355), 256, 0, stream>>>(
        x, xh, (int)(RAW / 4), qkv_w, proj_w, wq, wk, wv, wth, pwth, wTh);

    // 256x128 tiles: ceil(25092/256)=99 M-tiles x 18 N-tiles = 1782 blocks
    gemm256_qkv_kernel<<<dim3(99 * 18), 512, 0, stream>>>(
        xh, wth, qkv_b, BB * NTOK, q_raw, k_raw, v_raw);

    pool_ln_kernel<<<dim3(PL_NWG), 256, 0, stream>>>(
        q_raw, k_raw, v_raw, wTh, gq, bq, gk, bk, gv, bv,
        qph, kph, vpt);

    // single-pass attention: 25 q-tiles x 48 heads, fp16 out, no combine
    flash_attn_fp16_kernel<<<dim3(25, 48), 256, 0, stream>>>(
        qph, kph, vpt, aoh);

    gemm_fp16_kernel<6, false, float><<<dim3(50 * 6), 512, 0, stream>>>(
        aoh, pwth, proj_b, BB * NPOOL, (float*)d_out, nullptr, nullptr);
}